// Round 3
// baseline (213.330 us; speedup 1.0000x reference)
//
#include <hip/hip_runtime.h>
#include <math.h>

#ifndef M_PI
#define M_PI 3.14159265358979323846
#endif

constexpr int N     = 1024;
constexpr int M     = 4096;
constexpr int RANK  = 32;
constexpr int NTILE = 8;   // n-rows per einsum block

__device__ __forceinline__ float softplus_f(float x) {
    return (x > 0.0f) ? (x + log1pf(__expf(-x))) : log1pf(__expf(x));
}

// ---------------------------------------------------------------------------
// Kernel A: Hf[d][m] = sum_k softplus(H[d][k]) * exp(-2*pi*i*k*m/M)
// grid (M/256, RANK), block 256. Twiddle recurrence; step angle in double so
// only fp32 rotation rounding accumulates (~4e-4 rad over 4096 steps).
// ---------------------------------------------------------------------------
__global__ __launch_bounds__(256) void dft_kernel(const float* __restrict__ H,
                                                  float2* __restrict__ Hf) {
    __shared__ float sh[M];  // 16 KB
    const int d   = blockIdx.y;
    const int tid = threadIdx.x;
    for (int k = tid; k < M; k += 256) sh[k] = softplus_f(H[d * M + k]);
    __syncthreads();

    const int m = blockIdx.x * 256 + tid;
    const double ang = -2.0 * M_PI * (double)m / (double)M;
    const float wr = (float)cos(ang);
    const float wi = (float)sin(ang);

    float twr = 1.0f, twi = 0.0f;
    float re = 0.0f, im = 0.0f;
    #pragma unroll 8
    for (int k = 0; k < M; ++k) {
        const float h = sh[k];
        re = fmaf(h, twr, re);
        im = fmaf(h, twi, im);
        const float nr = fmaf(twr, wr, -twi * wi);
        const float ni = fmaf(twr, wi,  twi * wr);
        twr = nr; twi = ni;
    }
    Hf[d * M + m] = make_float2(re, im);
}

// ---------------------------------------------------------------------------
// Kernel B: V[n,m] = sum_d spW[n,d] * exp(-2*pi*i*tau[n,d]*m/M) * Hf[d,m]
// COMPLEX_OUT: write interleaved float2; else write real part only.
// ---------------------------------------------------------------------------
template <bool COMPLEX_OUT>
__global__ __launch_bounds__(256) void einsum_kernel(const float* __restrict__ W,
                                                     const float* __restrict__ tau,
                                                     const float2* __restrict__ Hf,
                                                     float* __restrict__ out_f) {
    __shared__ float sHr[16][256];
    __shared__ float sHi[16][256];
    __shared__ float sW[NTILE][RANK];
    __shared__ float sT[NTILE][RANK];

    const int tid   = threadIdx.x;
    const int mBase = blockIdx.x * 256;
    const int nBase = blockIdx.y * NTILE;

    for (int i = tid; i < NTILE * RANK; i += 256) {
        const int n  = i >> 5;
        const int dd = i & 31;
        sW[n][dd] = softplus_f(W[(nBase + n) * RANK + dd]);
        sT[n][dd] = tau[(nBase + n) * RANK + dd];
    }

    const int m = mBase + tid;
    const float phi = -2.0f * (float)M_PI * (float)m / (float)M;

    float accR[NTILE], accI[NTILE];
    #pragma unroll
    for (int n = 0; n < NTILE; ++n) { accR[n] = 0.0f; accI[n] = 0.0f; }

    for (int half = 0; half < 2; ++half) {
        __syncthreads();
        #pragma unroll
        for (int d = 0; d < 16; ++d) {
            const float2 v = Hf[(half * 16 + d) * M + m];
            sHr[d][tid] = v.x;
            sHi[d][tid] = v.y;
        }
        __syncthreads();

        #pragma unroll
        for (int n = 0; n < NTILE; ++n) {
            #pragma unroll
            for (int d = 0; d < 16; ++d) {
                const float t  = sT[n][half * 16 + d];
                const float ws = sW[n][half * 16 + d];
                float s, c;
                __sincosf(t * phi, &s, &c);
                const float cw = c * ws;
                const float sw = s * ws;
                const float hr = sHr[d][tid];
                const float hi = sHi[d][tid];
                accR[n] = fmaf(cw, hr, fmaf( sw, hi, accR[n]));
                if (COMPLEX_OUT)
                    accI[n] = fmaf(cw, hi, fmaf(-sw, hr, accI[n]));
            }
        }
    }

    #pragma unroll
    for (int n = 0; n < NTILE; ++n) {
        const size_t idx = (size_t)(nBase + n) * M + m;
        if (COMPLEX_OUT) ((float2*)out_f)[idx] = make_float2(accR[n], accI[n]);
        else             out_f[idx] = accR[n];
    }
}

// ---------------------------------------------------------------------------
// Kernel C (no-workspace fallback): finish the last ROWS output rows, whose
// storage holds the stashed Hf. Per-thread: read all 32 Hf values for this
// column into registers FIRST, then compute + overwrite. Columns are
// partitioned across blocks -> no cross-thread hazard.
// ---------------------------------------------------------------------------
template <bool COMPLEX_OUT>
__global__ __launch_bounds__(256) void tail_kernel(const float* __restrict__ W,
                                                   const float* __restrict__ tau,
                                                   float* __restrict__ out_f) {
    constexpr int ROWS  = COMPLEX_OUT ? RANK : 2 * RANK;  // 32 or 64
    const int nBase = N - ROWS;

    __shared__ float sW[ROWS][RANK];
    __shared__ float sT[ROWS][RANK];

    const int tid   = threadIdx.x;
    const int mBase = blockIdx.x * 256;

    for (int i = tid; i < ROWS * RANK; i += 256) {
        const int n  = i >> 5;
        const int dd = i & 31;
        sW[n][dd] = softplus_f(W[(nBase + n) * RANK + dd]);
        sT[n][dd] = tau[(nBase + n) * RANK + dd];
    }

    const int m = mBase + tid;
    // stash occupies exactly the storage of rows nBase..N-1
    const float2* stash = COMPLEX_OUT
        ? ((const float2*)out_f) + (size_t)nBase * M
        : (const float2*)(out_f + (size_t)nBase * M);

    float hr[RANK], hi[RANK];
    #pragma unroll
    for (int d = 0; d < RANK; ++d) {
        const float2 v = stash[(size_t)d * M + m];
        hr[d] = v.x; hi[d] = v.y;
    }
    __syncthreads();

    const float phi = -2.0f * (float)M_PI * (float)m / (float)M;

    for (int n = 0; n < ROWS; ++n) {
        float aR = 0.0f, aI = 0.0f;
        #pragma unroll
        for (int d = 0; d < RANK; ++d) {
            const float t  = sT[n][d];
            const float ws = sW[n][d];
            float s, c;
            __sincosf(t * phi, &s, &c);
            const float cw = c * ws;
            const float sw = s * ws;
            aR = fmaf(cw, hr[d], fmaf( sw, hi[d], aR));
            if (COMPLEX_OUT) aI = fmaf(cw, hi[d], fmaf(-sw, hr[d], aI));
        }
        const size_t idx = (size_t)(nBase + n) * M + m;
        if (COMPLEX_OUT) ((float2*)out_f)[idx] = make_float2(aR, aI);
        else             out_f[idx] = aR;   // safe: hr/hi already in registers
    }
}

// ---------------------------------------------------------------------------
extern "C" void kernel_launch(void* const* d_in, const int* in_sizes, int n_in,
                              void* d_out, int out_size, void* d_ws, size_t ws_size,
                              hipStream_t stream) {
    const float* W   = (const float*)d_in[0];   // (N, RANK)
    const float* H   = (const float*)d_in[1];   // (RANK, M)
    const float* tau = (const float*)d_in[2];   // (N, RANK)
    float* out_f = (float*)d_out;

    const bool   cplx     = (out_size >= 2 * N * M);  // interleaved complex?
    const size_t hf_bytes = (size_t)RANK * M * sizeof(float2);  // 1 MB

    if (d_ws != nullptr && ws_size >= hf_bytes) {
        float2* Hf = (float2*)d_ws;
        dft_kernel<<<dim3(M / 256, RANK), 256, 0, stream>>>(H, Hf);
        if (cplx)
            einsum_kernel<true ><<<dim3(M / 256, N / NTILE), 256, 0, stream>>>(W, tau, Hf, out_f);
        else
            einsum_kernel<false><<<dim3(M / 256, N / NTILE), 256, 0, stream>>>(W, tau, Hf, out_f);
    } else if (cplx) {
        // stash Hf in the storage of the last 32 complex rows
        float2* stash = ((float2*)out_f) + (size_t)(N - RANK) * M;
        dft_kernel<<<dim3(M / 256, RANK), 256, 0, stream>>>(H, stash);
        einsum_kernel<true ><<<dim3(M / 256, (N - RANK) / NTILE), 256, 0, stream>>>(W, tau, stash, out_f);
        tail_kernel<true ><<<dim3(M / 256), 256, 0, stream>>>(W, tau, out_f);
    } else {
        // stash Hf in the storage of the last 64 real rows
        float2* stash = (float2*)(out_f + (size_t)(N - 2 * RANK) * M);
        dft_kernel<<<dim3(M / 256, RANK), 256, 0, stream>>>(H, stash);
        einsum_kernel<false><<<dim3(M / 256, (N - 2 * RANK) / NTILE), 256, 0, stream>>>(W, tau, stash, out_f);
        tail_kernel<false><<<dim3(M / 256), 256, 0, stream>>>(W, tau, out_f);
    }
}

// Round 4
// 121.854 us; speedup vs baseline: 1.7507x; 1.7507x over previous
//
#include <hip/hip_runtime.h>
#include <math.h>

#ifndef M_PI
#define M_PI 3.14159265358979323846
#endif

constexpr int N    = 1024;
constexpr int M    = 4096;
constexpr int RANK = 32;
constexpr float PHI1 = -1.5339807878856412e-3f;   // -2*pi/4096

__device__ __forceinline__ float softplus_f(float x) {
    return (x > 0.0f) ? (x + log1pf(__expf(-x))) : log1pf(__expf(x));
}

// ===========================================================================
// DFT via Cooley-Tukey 64x64:  m = 64*m1 + r,  k = 64*k1 + k0
//   G[d][k0][r] = sum_k1 sp(h[d][64k1+k0]) * exp(-2pi*i*k1*r/64)
//   Hf[d][m]    = sum_k0 G[d][k0][m&63]    * exp(-2pi*i*k0*m/4096)
// Work: 17M MACs vs 536M brute-force.
// ===========================================================================

// Stage 1: grid (4 rGroups, 32 d), block 256. Thread: k0=tid&63, 4 r values.
// tw64 reads are wave-uniform (broadcast); sh reads conflict-free.
__global__ __launch_bounds__(256) void dft_stage1(const float* __restrict__ H,
                                                  float* __restrict__ GR,
                                                  float* __restrict__ GI) {
    __shared__ float sh[M];          // 16 KB
    __shared__ float tR[64], tI[64];
    const int d = blockIdx.y, tid = threadIdx.x;
    for (int k = tid; k < M; k += 256) sh[k] = softplus_f(H[d * M + k]);
    if (tid < 64) {
        const double a = -2.0 * M_PI * (double)tid / 64.0;
        tR[tid] = (float)cos(a); tI[tid] = (float)sin(a);
    }
    __syncthreads();

    const int k0    = tid & 63;
    const int rBase = blockIdx.x * 16 + (tid >> 6) * 4;
    float aR[4] = {0.f,0.f,0.f,0.f}, aI[4] = {0.f,0.f,0.f,0.f};
    int   idx[4] = {0,0,0,0};        // (k1 * (rBase+q)) & 63, incremental
    for (int k1 = 0; k1 < 64; ++k1) {
        const float hv = sh[(k1 << 6) + k0];
        #pragma unroll
        for (int q = 0; q < 4; ++q) {
            aR[q] = fmaf(hv, tR[idx[q]], aR[q]);
            aI[q] = fmaf(hv, tI[idx[q]], aI[q]);
            idx[q] = (idx[q] + rBase + q) & 63;
        }
    }
    #pragma unroll
    for (int q = 0; q < 4; ++q) {
        GR[d * 4096 + (k0 << 6) + rBase + q] = aR[q];
        GI[d * 4096 + (k0 << 6) + rBase + q] = aI[q];
    }
}

// Stage 2: grid (16 mGroups, 32 d), block 256, one m per thread.
// G row staged planar in LDS (reads r-consecutive -> 2-way only, free).
__global__ __launch_bounds__(256) void dft_stage2(const float* __restrict__ GR,
                                                  const float* __restrict__ GI,
                                                  float2* __restrict__ Hf) {
    __shared__ float sR[4096], sI[4096];   // 32 KB
    const int d = blockIdx.y, tid = threadIdx.x;
    for (int i = tid; i < 4096; i += 256) { sR[i] = GR[d*4096 + i]; sI[i] = GI[d*4096 + i]; }
    __syncthreads();

    const int m = blockIdx.x * 256 + tid;
    const int r = m & 63;
    float ss, sc; __sincosf(PHI1 * (float)m, &ss, &sc);   // step e^{-2pi i m/4096}
    float twR = 1.f, twI = 0.f, accR = 0.f, accI = 0.f;
    #pragma unroll 8
    for (int k0 = 0; k0 < 64; ++k0) {
        const float gr = sR[(k0 << 6) + r], gi = sI[(k0 << 6) + r];
        accR = fmaf(twR, gr, fmaf(-twI, gi, accR));
        accI = fmaf(twR, gi, fmaf( twI, gr, accI));
        const float nR = fmaf(twR, sc, -twI * ss);
        const float nI = fmaf(twR, ss,  twI * sc);
        twR = nR; twI = nI;
    }
    Hf[d * M + m] = make_float2(accR, accI);
}

// Fused fallback (no G workspace): grid (4 mGroups, 32 d); G in padded LDS.
__global__ __launch_bounds__(256) void dft_fused(const float* __restrict__ H,
                                                 float2* __restrict__ Hf) {
    __shared__ float sh[M];                  // 16 KB
    __shared__ float tR[64], tI[64];
    __shared__ float sR[64 * 65], sI[64 * 65];  // padded stride 65: conflict-free
    const int d = blockIdx.y, tid = threadIdx.x;
    for (int k = tid; k < M; k += 256) sh[k] = softplus_f(H[d * M + k]);
    if (tid < 64) {
        const double a = -2.0 * M_PI * (double)tid / 64.0;
        tR[tid] = (float)cos(a); tI[tid] = (float)sin(a);
    }
    __syncthreads();

    const int k0 = tid & 63;
    const int rB = (tid >> 6) * 16;
    for (int rr = 0; rr < 16; ++rr) {
        const int r = rB + rr;
        float aR = 0.f, aI = 0.f; int idx = 0;
        for (int k1 = 0; k1 < 64; ++k1) {
            const float hv = sh[(k1 << 6) + k0];
            aR = fmaf(hv, tR[idx], aR);
            aI = fmaf(hv, tI[idx], aI);
            idx = (idx + r) & 63;
        }
        sR[k0 * 65 + r] = aR; sI[k0 * 65 + r] = aI;
    }
    __syncthreads();

    const int mBase = blockIdx.x * 1024;
    for (int j = 0; j < 4; ++j) {
        const int m = mBase + j * 256 + tid;
        const int r = m & 63;
        float ss, sc; __sincosf(PHI1 * (float)m, &ss, &sc);
        float twR = 1.f, twI = 0.f, accR = 0.f, accI = 0.f;
        #pragma unroll 8
        for (int q = 0; q < 64; ++q) {
            const float gr = sR[q * 65 + r], gi = sI[q * 65 + r];
            accR = fmaf(twR, gr, fmaf(-twI, gi, accR));
            accI = fmaf(twR, gi, fmaf( twI, gr, accI));
            const float nR = fmaf(twR, sc, -twI * ss);
            const float nI = fmaf(twR, ss,  twI * sc);
            twR = nR; twI = nI;
        }
        Hf[d * M + m] = make_float2(accR, accI);
    }
}

// ===========================================================================
// Einsum: V[n,m] = sum_d spW[n,d] * e^{-2pi i tau[n,d] m/M} * Hf[d,m]
// Thread owns (n, 16 consecutive m). Per d: 2 sincos seed tw/step, then 16
// recurrence steps (8 fma each). Hf tile in LDS, swizzled for conflict-free
// stride-16 reads: element mm stored at p=(mm&0xF0)|((mm+(mm>>4))&15).
// ===========================================================================
template <bool CPLX>
__global__ __launch_bounds__(256) void einsum_kernel(const float* __restrict__ W,
                                                     const float* __restrict__ tau,
                                                     const float2* __restrict__ Hf,
                                                     float* __restrict__ out_f) {
    __shared__ float2 sHf[16 * 256];          // 32 KB (one 16-d half)
    __shared__ float  sW[16][RANK], sT[16][RANK];  // 4 KB
    const int tid   = threadIdx.x;
    const int mBase = blockIdx.x * 256;
    const int nBase = blockIdx.y * 16;

    for (int i = tid; i < 16 * RANK; i += 256) {
        const int n_ = i >> 5, dd = i & 31;
        sW[n_][dd] = softplus_f(W[(nBase + n_) * RANK + dd]);
        sT[n_][dd] = tau[(nBase + n_) * RANK + dd];
    }

    const int nl = tid >> 4, chunk = tid & 15;
    const int m0 = mBase + chunk * 16;

    float accR[16], accI[16];
    #pragma unroll
    for (int j = 0; j < 16; ++j) { accR[j] = 0.f; accI[j] = 0.f; }

    for (int half = 0; half < 2; ++half) {
        __syncthreads();   // protect previous half's readers (and sW/sT at half 0)
        for (int i = tid; i < 16 * 256; i += 256) {
            const int dl = i >> 8, mm = i & 255;
            const int p  = (mm & 0xF0) | ((mm + (mm >> 4)) & 15);
            sHf[(dl << 8) + p] = Hf[(half * 16 + dl) * M + mBase + mm];
        }
        __syncthreads();

        for (int dl = 0; dl < 16; ++dl) {
            const int dd = half * 16 + dl;
            const float t = sT[nl][dd], w = sW[nl][dd];
            const float astep = PHI1 * t;               // -2pi*tau/M
            float ss, sc; __sincosf(astep, &ss, &sc);
            float s0, c0; __sincosf(astep * (float)m0, &s0, &c0);
            float twR = w * c0, twI = w * s0;           // spW folded into tw
            #pragma unroll
            for (int j = 0; j < 16; ++j) {
                const float2 h = sHf[(dl << 8) + (chunk << 4) + ((j + chunk) & 15)];
                accR[j] = fmaf(twR, h.x, fmaf(-twI, h.y, accR[j]));
                if (CPLX) accI[j] = fmaf(twR, h.y, fmaf(twI, h.x, accI[j]));
                const float nR2 = fmaf(twR, sc, -twI * ss);
                const float nI2 = fmaf(twR, ss,  twI * sc);
                twR = nR2; twI = nI2;
            }
        }
    }

    const int n = nBase + nl;
    float4* o4 = (float4*)out_f;
    if (CPLX) {
        const size_t base = ((size_t)n * M + m0) >> 1;
        #pragma unroll
        for (int jj = 0; jj < 8; ++jj)
            o4[base + jj] = make_float4(accR[2*jj], accI[2*jj], accR[2*jj+1], accI[2*jj+1]);
    } else {
        const size_t base = ((size_t)n * M + m0) >> 2;
        #pragma unroll
        for (int jj = 0; jj < 4; ++jj)
            o4[base + jj] = make_float4(accR[4*jj], accR[4*jj+1], accR[4*jj+2], accR[4*jj+3]);
    }
}

// ===========================================================================
// Tail (no-workspace fallback only) — unchanged from round 3 (known-good).
// ===========================================================================
template <bool COMPLEX_OUT>
__global__ __launch_bounds__(256) void tail_kernel(const float* __restrict__ W,
                                                   const float* __restrict__ tau,
                                                   float* __restrict__ out_f) {
    constexpr int ROWS = COMPLEX_OUT ? RANK : 2 * RANK;
    const int nBase = N - ROWS;
    __shared__ float sW[ROWS][RANK];
    __shared__ float sT[ROWS][RANK];
    const int tid = threadIdx.x;
    const int mBase = blockIdx.x * 256;
    for (int i = tid; i < ROWS * RANK; i += 256) {
        const int n_ = i >> 5, dd = i & 31;
        sW[n_][dd] = softplus_f(W[(nBase + n_) * RANK + dd]);
        sT[n_][dd] = tau[(nBase + n_) * RANK + dd];
    }
    const int m = mBase + tid;
    const float2* stash = COMPLEX_OUT
        ? ((const float2*)out_f) + (size_t)nBase * M
        : (const float2*)(out_f + (size_t)nBase * M);
    float hr[RANK], hi[RANK];
    #pragma unroll
    for (int d = 0; d < RANK; ++d) {
        const float2 v = stash[(size_t)d * M + m];
        hr[d] = v.x; hi[d] = v.y;
    }
    __syncthreads();
    const float phi = PHI1 * (float)m;
    for (int n_ = 0; n_ < ROWS; ++n_) {
        float aR = 0.f, aI = 0.f;
        #pragma unroll
        for (int d = 0; d < RANK; ++d) {
            const float t = sT[n_][d], ws = sW[n_][d];
            float s, c;
            __sincosf(t * phi, &s, &c);
            const float cw = c * ws, sw = s * ws;
            aR = fmaf(cw, hr[d], fmaf(-sw, hi[d], aR));
            if (COMPLEX_OUT) aI = fmaf(cw, hi[d], fmaf(sw, hr[d], aI));
        }
        const size_t idx = (size_t)(nBase + n_) * M + m;
        if (COMPLEX_OUT) ((float2*)out_f)[idx] = make_float2(aR, aI);
        else             out_f[idx] = aR;
    }
}

// ---------------------------------------------------------------------------
extern "C" void kernel_launch(void* const* d_in, const int* in_sizes, int n_in,
                              void* d_out, int out_size, void* d_ws, size_t ws_size,
                              hipStream_t stream) {
    const float* W   = (const float*)d_in[0];
    const float* H   = (const float*)d_in[1];
    const float* tau = (const float*)d_in[2];
    float* out_f = (float*)d_out;

    const bool   cplx = (out_size >= 2 * N * M);
    const size_t HF_B = (size_t)RANK * M * sizeof(float2);  // 1 MB
    const size_t G_B  = (size_t)RANK * M * sizeof(float);   // 512 KB

    if (d_ws != nullptr && ws_size >= HF_B + 2 * G_B) {
        float2* Hf = (float2*)d_ws;
        float*  GR = (float*)((char*)d_ws + HF_B);
        float*  GI = (float*)((char*)d_ws + HF_B + G_B);
        dft_stage1<<<dim3(4, 32), 256, 0, stream>>>(H, GR, GI);
        dft_stage2<<<dim3(16, 32), 256, 0, stream>>>(GR, GI, Hf);
        if (cplx) einsum_kernel<true ><<<dim3(16, N / 16), 256, 0, stream>>>(W, tau, Hf, out_f);
        else      einsum_kernel<false><<<dim3(16, N / 16), 256, 0, stream>>>(W, tau, Hf, out_f);
    } else if (d_ws != nullptr && ws_size >= HF_B) {
        float2* Hf = (float2*)d_ws;
        dft_fused<<<dim3(4, 32), 256, 0, stream>>>(H, Hf);
        if (cplx) einsum_kernel<true ><<<dim3(16, N / 16), 256, 0, stream>>>(W, tau, Hf, out_f);
        else      einsum_kernel<false><<<dim3(16, N / 16), 256, 0, stream>>>(W, tau, Hf, out_f);
    } else if (cplx) {
        float2* stash = ((float2*)out_f) + (size_t)(N - RANK) * M;
        dft_fused<<<dim3(4, 32), 256, 0, stream>>>(H, stash);
        einsum_kernel<true ><<<dim3(16, (N - RANK) / 16), 256, 0, stream>>>(W, tau, (const float2*)stash, out_f);
        tail_kernel<true ><<<dim3(16), 256, 0, stream>>>(W, tau, out_f);
    } else {
        float2* stash = (float2*)(out_f + (size_t)(N - 2 * RANK) * M);
        dft_fused<<<dim3(4, 32), 256, 0, stream>>>(H, stash);
        einsum_kernel<false><<<dim3(16, (N - 2 * RANK) / 16), 256, 0, stream>>>(W, tau, (const float2*)stash, out_f);
        tail_kernel<false><<<dim3(16), 256, 0, stream>>>(W, tau, out_f);
    }
}

// Round 5
// 120.710 us; speedup vs baseline: 1.7673x; 1.0095x over previous
//
#include <hip/hip_runtime.h>
#include <math.h>

#ifndef M_PI
#define M_PI 3.14159265358979323846
#endif

constexpr int N    = 1024;
constexpr int M    = 4096;
constexpr int RANK = 32;
constexpr float PHI1 = -1.5339807878856412e-3f;   // -2*pi/4096

__device__ __forceinline__ float softplus_f(float x) {
    return (x > 0.0f) ? (x + log1pf(__expf(-x))) : log1pf(__expf(x));
}

// ===========================================================================
// Fused Cooley-Tukey 64x64 DFT of softplus(H): writes PLANAR HfR / HfI.
// grid (4 mGroups x 32 d), block 256.
// Phase 1: G[k0][r] = sum_k1 h[64k1+k0] e^{-2pi i k1 r/64} — 16 in-register
//          rotation chains per thread (1 LDS read + 96 fma per k1).
// Phase 2: Hf[m] = sum_k0 G[k0][m&63] e^{-2pi i k0 m/4096} — register chain.
// ===========================================================================
__global__ __launch_bounds__(256) void dft_fused(const float* __restrict__ H,
                                                 float* __restrict__ HfR,
                                                 float* __restrict__ HfI) {
    __shared__ float  sh[M];             // 16 KB
    __shared__ float2 sG[64 * 65];       // 33.3 KB, pad 65 (phase-2 reads conflict-free)
    const int d = blockIdx.y, tid = threadIdx.x;
    for (int k = tid; k < M; k += 256) sh[k] = softplus_f(H[d * M + k]);
    __syncthreads();

    const int k0 = tid & 63;
    const int rB = (tid >> 6) * 16;
    float twR[16], twI[16], stR[16], stI[16], aR[16], aI[16];
    #pragma unroll
    for (int rr = 0; rr < 16; ++rr) {
        const float ang = (-2.0f * (float)M_PI / 64.0f) * (float)(rB + rr);
        __sincosf(ang, &stI[rr], &stR[rr]);     // step e^{-2pi i r/64}
        twR[rr] = 1.f; twI[rr] = 0.f; aR[rr] = 0.f; aI[rr] = 0.f;
    }
    for (int k1 = 0; k1 < 64; ++k1) {
        const float h = sh[(k1 << 6) + k0];
        #pragma unroll
        for (int rr = 0; rr < 16; ++rr) {
            aR[rr] = fmaf(h, twR[rr], aR[rr]);
            aI[rr] = fmaf(h, twI[rr], aI[rr]);
            const float nR = fmaf(twR[rr], stR[rr], -twI[rr] * stI[rr]);
            const float nI = fmaf(twR[rr], stI[rr],  twI[rr] * stR[rr]);
            twR[rr] = nR; twI[rr] = nI;
        }
    }
    #pragma unroll
    for (int rr = 0; rr < 16; ++rr)
        sG[k0 * 65 + rB + rr] = make_float2(aR[rr], aI[rr]);
    __syncthreads();

    const int mBase = blockIdx.x * 1024;
    for (int j = 0; j < 4; ++j) {
        const int m = mBase + j * 256 + tid;
        const int r = m & 63;
        float ss, sc; __sincosf(PHI1 * (float)m, &ss, &sc);   // e^{-2pi i m/4096}
        float tR_ = 1.f, tI_ = 0.f, accR = 0.f, accI = 0.f;
        #pragma unroll 8
        for (int q = 0; q < 64; ++q) {
            const float2 g = sG[q * 65 + r];
            accR = fmaf(tR_, g.x, fmaf(-tI_, g.y, accR));
            accI = fmaf(tR_, g.y, fmaf( tI_, g.x, accI));
            const float nR = fmaf(tR_, sc, -tI_ * ss);
            const float nI = fmaf(tR_, ss,  tI_ * sc);
            tR_ = nR; tI_ = nI;
        }
        HfR[d * M + m] = accR;
        HfI[d * M + m] = accI;
    }
}

// ===========================================================================
// Einsum: V[n,m] = sum_d spW[n,d] e^{-2pi i tau[n,d] m/M} Hf[d,m]  (planar Hf)
// grid (16 mGroups x rows/16), block 256. Thread owns (n, m = mBase+chunk+16j).
// Strided chunks -> LDS reads are 16-way-broadcast conflict-free, idx += 16.
// ===========================================================================
template <bool CPLX>
__global__ __launch_bounds__(256) void einsum_kernel(const float* __restrict__ W,
                                                     const float* __restrict__ tau,
                                                     const float* __restrict__ HfR,
                                                     const float* __restrict__ HfI,
                                                     float* __restrict__ out_f) {
    __shared__ float sR[16 * 256], sI[16 * 256];     // 32 KB
    __shared__ float sW[16][RANK], sT[16][RANK];     // 4 KB
    const int tid   = threadIdx.x;
    const int mBase = blockIdx.x * 256;
    const int nBase = blockIdx.y * 16;

    for (int i = tid; i < 16 * RANK; i += 256) {
        const int n_ = i >> 5, dd = i & 31;
        sW[n_][dd] = softplus_f(W[(nBase + n_) * RANK + dd]);
        sT[n_][dd] = tau[(nBase + n_) * RANK + dd];
    }

    const int nl = tid >> 4, chunk = tid & 15;
    const int m0 = mBase + chunk;

    float accR[16], accI[16];
    #pragma unroll
    for (int j = 0; j < 16; ++j) { accR[j] = 0.f; if (CPLX) accI[j] = 0.f; }

    for (int half = 0; half < 2; ++half) {
        __syncthreads();
        for (int i4 = tid; i4 < 1024; i4 += 256) {       // 16 d x 64 float4
            const int dl = i4 >> 6, g = i4 & 63;
            ((float4*)sR)[(dl << 6) + g] =
                *(const float4*)(HfR + (half * 16 + dl) * M + mBase + (g << 2));
            ((float4*)sI)[(dl << 6) + g] =
                *(const float4*)(HfI + (half * 16 + dl) * M + mBase + (g << 2));
        }
        __syncthreads();

        #pragma unroll 2
        for (int dl = 0; dl < 16; ++dl) {
            const int dd = (half << 4) + dl;
            const float t = sT[nl][dd], w = sW[nl][dd];
            const float a1 = PHI1 * t;
            float ss, sc; __sincosf(a1 * 16.0f, &ss, &sc);       // stride-16 step
            float s0, c0; __sincosf(a1 * (float)m0, &s0, &c0);
            float tR_ = w * c0, tI_ = w * s0;
            int idx = (dl << 8) + chunk;
            #pragma unroll
            for (int j = 0; j < 16; ++j) {
                const float hr = sR[idx], hi = sI[idx];
                accR[j] = fmaf(tR_, hr, fmaf(-tI_, hi, accR[j]));
                if (CPLX) accI[j] = fmaf(tR_, hi, fmaf(tI_, hr, accI[j]));
                const float nR = fmaf(tR_, sc, -tI_ * ss);
                const float nI = fmaf(tR_, ss,  tI_ * sc);
                tR_ = nR; tI_ = nI;
                idx += 16;
            }
        }
    }

    const int n = nBase + nl;
    if (CPLX) {
        float2* o2 = (float2*)out_f;
        #pragma unroll
        for (int j = 0; j < 16; ++j)
            o2[(size_t)n * M + m0 + (j << 4)] = make_float2(accR[j], accI[j]);
    } else {
        #pragma unroll
        for (int j = 0; j < 16; ++j)
            out_f[(size_t)n * M + m0 + (j << 4)] = accR[j];
    }
}

// ===========================================================================
// Tail (real, no-ws): rows 960..1023, whose storage is the planar stash.
// grid 128 blocks x 32-col windows. Block's read-set == write-set
// (rows 960-1023 x cols [c0,c0+32)) -> stage to LDS, barrier, then write:
// provably race-free (no cross-block overlap).
// ===========================================================================
__global__ __launch_bounds__(256) void tail_real(const float* __restrict__ W,
                                                 const float* __restrict__ tau,
                                                 const float* __restrict__ stashR,
                                                 const float* __restrict__ stashI,
                                                 float* __restrict__ out_f) {
    __shared__ float stR[32 * 32], stI[32 * 32];     // 8 KB
    __shared__ float sW[64][RANK], sT[64][RANK];     // 16 KB
    const int tid = threadIdx.x;
    const int c0  = blockIdx.x * 32;
    const int nBase = N - 64;    // 960

    for (int i = tid; i < 64 * RANK; i += 256) {
        const int n_ = i >> 5, dd = i & 31;
        sW[n_][dd] = softplus_f(W[(nBase + n_) * RANK + dd]);
        sT[n_][dd] = tau[(nBase + n_) * RANK + dd];
    }
    for (int i = tid; i < 32 * 32; i += 256) {
        const int d_ = i >> 5, mm = i & 31;
        stR[i] = stashR[d_ * M + c0 + mm];
        stI[i] = stashI[d_ * M + c0 + mm];
    }
    __syncthreads();   // ALL stash reads staged before ANY write below

    const int n = tid >> 2, chunk = tid & 3;
    const int m0 = c0 + chunk;
    float acc[8];
    #pragma unroll
    for (int j = 0; j < 8; ++j) acc[j] = 0.f;

    for (int d = 0; d < RANK; ++d) {
        const float t = sT[n][d], w = sW[n][d];
        const float a1 = PHI1 * t;
        float ss, sc; __sincosf(a1 * 4.0f, &ss, &sc);     // stride-4 step
        float s0, c0f; __sincosf(a1 * (float)m0, &s0, &c0f);
        float tR_ = w * c0f, tI_ = w * s0;
        int idx = (d << 5) + chunk;
        #pragma unroll
        for (int j = 0; j < 8; ++j) {
            acc[j] = fmaf(tR_, stR[idx], fmaf(-tI_, stI[idx], acc[j]));
            const float nR = fmaf(tR_, sc, -tI_ * ss);
            const float nI = fmaf(tR_, ss,  tI_ * sc);
            tR_ = nR; tI_ = nI;
            idx += 4;
        }
    }
    #pragma unroll
    for (int j = 0; j < 8; ++j)
        out_f[(size_t)(nBase + n) * M + m0 + (j << 2)] = acc[j];
}

// ===========================================================================
// Tail (cplx, no-ws fallback — believed dead path; validated pattern from r4):
// per-thread upfront register read of all 32 stash values, then overwrite.
// ===========================================================================
__global__ __launch_bounds__(256) void tail_cplx(const float* __restrict__ W,
                                                 const float* __restrict__ tau,
                                                 const float* __restrict__ stashR,
                                                 const float* __restrict__ stashI,
                                                 float* __restrict__ out_f) {
    const int nBase = N - 32;    // 992
    __shared__ float sW[32][RANK], sT[32][RANK];
    const int tid = threadIdx.x, mBase = blockIdx.x * 256;
    for (int i = tid; i < 32 * RANK; i += 256) {
        const int n_ = i >> 5, dd = i & 31;
        sW[n_][dd] = softplus_f(W[(nBase + n_) * RANK + dd]);
        sT[n_][dd] = tau[(nBase + n_) * RANK + dd];
    }
    const int m = mBase + tid;
    float hr[RANK], hi[RANK];
    #pragma unroll
    for (int d = 0; d < RANK; ++d) { hr[d] = stashR[d * M + m]; hi[d] = stashI[d * M + m]; }
    __syncthreads();
    const float phi = PHI1 * (float)m;
    for (int n_ = 0; n_ < 32; ++n_) {
        float aR = 0.f, aI = 0.f;
        #pragma unroll
        for (int d = 0; d < RANK; ++d) {
            const float t = sT[n_][d], w = sW[n_][d];
            float s, c; __sincosf(t * phi, &s, &c);
            const float cw = c * w, sw = s * w;
            aR = fmaf(cw, hr[d], fmaf(-sw, hi[d], aR));
            aI = fmaf(cw, hi[d], fmaf( sw, hr[d], aI));
        }
        ((float2*)out_f)[(size_t)(nBase + n_) * M + m] = make_float2(aR, aI);
    }
}

// ---------------------------------------------------------------------------
extern "C" void kernel_launch(void* const* d_in, const int* in_sizes, int n_in,
                              void* d_out, int out_size, void* d_ws, size_t ws_size,
                              hipStream_t stream) {
    const float* W   = (const float*)d_in[0];
    const float* H   = (const float*)d_in[1];
    const float* tau = (const float*)d_in[2];
    float* out_f = (float*)d_out;

    const bool   cplx   = (out_size >= 2 * N * M);
    const size_t planeN = (size_t)RANK * M;            // 131072 floats / plane

    if (d_ws != nullptr && ws_size >= 2 * planeN * sizeof(float)) {
        float* HfR = (float*)d_ws;
        float* HfI = HfR + planeN;
        dft_fused<<<dim3(4, 32), 256, 0, stream>>>(H, HfR, HfI);
        if (cplx) einsum_kernel<true ><<<dim3(16, N / 16), 256, 0, stream>>>(W, tau, HfR, HfI, out_f);
        else      einsum_kernel<false><<<dim3(16, N / 16), 256, 0, stream>>>(W, tau, HfR, HfI, out_f);
    } else if (!cplx) {
        // stash planes in the storage of the last 64 real rows
        float* HfR = out_f + (size_t)(N - 64) * M;
        float* HfI = HfR + planeN;
        dft_fused<<<dim3(4, 32), 256, 0, stream>>>(H, HfR, HfI);
        einsum_kernel<false><<<dim3(16, (N - 64) / 16), 256, 0, stream>>>(W, tau, HfR, HfI, out_f);
        tail_real<<<dim3(128), 256, 0, stream>>>(W, tau, HfR, HfI, out_f);
    } else {
        // stash planes in the storage of the last 32 complex rows
        float* HfR = out_f + 2 * (size_t)N * M - 2 * planeN;
        float* HfI = HfR + planeN;
        dft_fused<<<dim3(4, 32), 256, 0, stream>>>(H, HfR, HfI);
        einsum_kernel<true ><<<dim3(16, (N - 32) / 16), 256, 0, stream>>>(W, tau, HfR, HfI, out_f);
        tail_cplx<<<dim3(16), 256, 0, stream>>>(W, tau, HfR, HfI, out_f);
    }
}